// Round 12
// baseline (625.713 us; speedup 1.0000x reference)
//
#include <hip/hip_runtime.h>

// ---------------------------------------------------------------------------
// RPN forward, MI355X. Only batch element 7 contributes to the output.
// transposeW -> conv3x3 v3 (lane=2oc, 16 cin-splits for occupancy) ->
// reduce+leaky -> 1x1 heads -> decode/score/key (+rank zero-init) ->
// O(N^2) rank sort -> top-6000 -> NMS bitmask (yy2=max bug replicated) ->
// word-serial scan (ALU in-block loop + batched kept-row loads) -> 300x4.
// Deterministic fp32 everywhere. Tail buffers alias the dead part region.
// ---------------------------------------------------------------------------

#define NPIX 2500      // 50*50
#define NANCH 22500    // 2500*9
#define NKEY 22528     // NANCH padded to 88*256 (sentinel tail)
#define PRE 6000
#define MASKW 94       // ceil(6000/64) usable words
#define MW 96          // storage stride in words
#define JCHUNK 1536    // j-chunk for mask kernel (24 words)
#define CS 16          // cin splits for conv3x3 (3200 waves = 12.5/CU)
#define KSLOT 8        // static kept-row load slots per block in scan

// ---------------- weight transpose: wt(oc,cin*9) -> wtT(cin*9,oc) ----------
__global__ __launch_bounds__(256) void transposeW(
    const float* __restrict__ wt,   // (512, 4608)
    float* __restrict__ wtT)        // (4608, 512)
{
    __shared__ float T[64][65];
    const int tid = threadIdx.x;
    const int c   = tid & 63;
    const int r4  = tid >> 6;
    const int ct0 = blockIdx.x * 64;
    const int ocb = blockIdx.y * 64;
    #pragma unroll
    for (int i = 0; i < 16; ++i) {
        const int o = r4 + i * 4;
        T[o][c] = wt[(size_t)(ocb + o) * 4608 + ct0 + c];
    }
    __syncthreads();
    #pragma unroll
    for (int i = 0; i < 16; ++i) {
        const int ctl = r4 + i * 4;
        wtT[(size_t)(ct0 + ctl) * 512 + ocb + c] = T[c][ctl];
    }
}

// ---------------- conv 3x3 v3: lane = 2 oc (o, o+64), wave = one row -------
// grid (4 ocGroups, 50 rows, 16 cin groups), block 64 (1 wave).
// Per cin: 18 coalesced weight loads, 3-row LDS window (b128 broadcast
// reads), 50 px x 2 oc x 9 taps = 900 FMA. 3200 waves = 3.1/SIMD.
__global__ __launch_bounds__(64) void conv3x3_v3(
    const float* __restrict__ x,    // batch-7 base (512,50,50)
    const float* __restrict__ wtT,  // (4608, 512)
    float* __restrict__ part)       // (CS, 2500, 512)
{
    __shared__ __align__(16) float sRow[3 * 56];  // col0 + cols51..55 are pad
    const int lane = threadIdx.x;
    const int ocb  = blockIdx.x * 128;
    const int r    = blockIdx.y;                 // 0..49 (wave-uniform)
    const int cing = blockIdx.z * 32;

    const float m0 = (r > 0)  ? 1.0f : 0.0f;
    const float m2 = (r < 49) ? 1.0f : 0.0f;
    const int  sr0 = (r > 0)  ? r - 1 : 0;
    const int  sr2 = (r < 49) ? r + 1 : 49;

    if (lane < 18) {                              // zero pad cols {0, 51..55}
        const int rr = lane / 6;
        const int cc = lane - rr * 6;
        const int col = (cc == 0) ? 0 : (50 + cc);
        sRow[rr * 56 + col] = 0.0f;
    }

    float accA[50], accB[50];
    #pragma unroll
    for (int p = 0; p < 50; ++p) { accA[p] = 0.f; accB[p] = 0.f; }

    for (int cin = 0; cin < 32; ++cin) {
        const float* xp = x + (size_t)(cing + cin) * NPIX;
        if (lane < 50) {
            sRow[0 * 56 + 1 + lane] = xp[sr0 * 50 + lane] * m0;
            sRow[1 * 56 + 1 + lane] = xp[r   * 50 + lane];
            sRow[2 * 56 + 1 + lane] = xp[sr2 * 50 + lane] * m2;
        }
        const float* wp = wtT + (size_t)(cing + cin) * 9 * 512 + ocb + lane;
        float wA[9], wB[9];
        #pragma unroll
        for (int t = 0; t < 9; ++t) {
            wA[t] = wp[(size_t)t * 512];
            wB[t] = wp[(size_t)t * 512 + 64];
        }

        const float4* R0 = (const float4*)(sRow + 0 * 56);
        const float4* R1 = (const float4*)(sRow + 1 * 56);
        const float4* R2 = (const float4*)(sRow + 2 * 56);

        float4 q0, q1, q2;
        q0 = q1 = q2 = make_float4(0.f, 0.f, 0.f, 0.f);
        #pragma unroll
        for (int B = 0; B < 13; ++B) {
            const float4 n0 = R0[B];
            const float4 n1 = R1[B];
            const float4 n2 = R2[B];
            if (B > 0) {
                const int p = 4 * B - 2;
                {
                    float a = accA[p], b = accB[p];
                    a = fmaf(wA[0], q0.z, a); a = fmaf(wA[1], q0.w, a); a = fmaf(wA[2], n0.x, a);
                    a = fmaf(wA[3], q1.z, a); a = fmaf(wA[4], q1.w, a); a = fmaf(wA[5], n1.x, a);
                    a = fmaf(wA[6], q2.z, a); a = fmaf(wA[7], q2.w, a); a = fmaf(wA[8], n2.x, a);
                    b = fmaf(wB[0], q0.z, b); b = fmaf(wB[1], q0.w, b); b = fmaf(wB[2], n0.x, b);
                    b = fmaf(wB[3], q1.z, b); b = fmaf(wB[4], q1.w, b); b = fmaf(wB[5], n1.x, b);
                    b = fmaf(wB[6], q2.z, b); b = fmaf(wB[7], q2.w, b); b = fmaf(wB[8], n2.x, b);
                    accA[p] = a; accB[p] = b;
                }
                {
                    float a = accA[p + 1], b = accB[p + 1];
                    a = fmaf(wA[0], q0.w, a); a = fmaf(wA[1], n0.x, a); a = fmaf(wA[2], n0.y, a);
                    a = fmaf(wA[3], q1.w, a); a = fmaf(wA[4], n1.x, a); a = fmaf(wA[5], n1.y, a);
                    a = fmaf(wA[6], q2.w, a); a = fmaf(wA[7], n2.x, a); a = fmaf(wA[8], n2.y, a);
                    b = fmaf(wB[0], q0.w, b); b = fmaf(wB[1], n0.x, b); b = fmaf(wB[2], n0.y, b);
                    b = fmaf(wB[3], q1.w, b); b = fmaf(wB[4], n1.x, b); b = fmaf(wB[5], n1.y, b);
                    b = fmaf(wB[6], q2.w, b); b = fmaf(wB[7], n2.x, b); b = fmaf(wB[8], n2.y, b);
                    accA[p + 1] = a; accB[p + 1] = b;
                }
            }
            {
                const int p = 4 * B;
                {
                    float a = accA[p], b = accB[p];
                    a = fmaf(wA[0], n0.x, a); a = fmaf(wA[1], n0.y, a); a = fmaf(wA[2], n0.z, a);
                    a = fmaf(wA[3], n1.x, a); a = fmaf(wA[4], n1.y, a); a = fmaf(wA[5], n1.z, a);
                    a = fmaf(wA[6], n2.x, a); a = fmaf(wA[7], n2.y, a); a = fmaf(wA[8], n2.z, a);
                    b = fmaf(wB[0], n0.x, b); b = fmaf(wB[1], n0.y, b); b = fmaf(wB[2], n0.z, b);
                    b = fmaf(wB[3], n1.x, b); b = fmaf(wB[4], n1.y, b); b = fmaf(wB[5], n1.z, b);
                    b = fmaf(wB[6], n2.x, b); b = fmaf(wB[7], n2.y, b); b = fmaf(wB[8], n2.z, b);
                    accA[p] = a; accB[p] = b;
                }
                {
                    float a = accA[p + 1], b = accB[p + 1];
                    a = fmaf(wA[0], n0.y, a); a = fmaf(wA[1], n0.z, a); a = fmaf(wA[2], n0.w, a);
                    a = fmaf(wA[3], n1.y, a); a = fmaf(wA[4], n1.z, a); a = fmaf(wA[5], n1.w, a);
                    a = fmaf(wA[6], n2.y, a); a = fmaf(wA[7], n2.z, a); a = fmaf(wA[8], n2.w, a);
                    b = fmaf(wB[0], n0.y, b); b = fmaf(wB[1], n0.z, b); b = fmaf(wB[2], n0.w, b);
                    b = fmaf(wB[3], n1.y, b); b = fmaf(wB[4], n1.z, b); b = fmaf(wB[5], n1.w, b);
                    b = fmaf(wB[6], n2.y, b); b = fmaf(wB[7], n2.z, b); b = fmaf(wB[8], n2.w, b);
                    accA[p + 1] = a; accB[p + 1] = b;
                }
            }
            q0 = n0; q1 = n1; q2 = n2;
        }
    }

    float* dst = part + ((size_t)blockIdx.z * NPIX + r * 50) * 512 + ocb + lane;
    #pragma unroll
    for (int p = 0; p < 50; ++p) {
        dst[(size_t)p * 512]      = accA[p];
        dst[(size_t)p * 512 + 64] = accB[p];
    }
}

// ---------------- reduce partials + bias + leaky + transpose ---------------
__global__ __launch_bounds__(256) void reduce_leaky(
    const float* __restrict__ part, const float* __restrict__ bias,
    float* __restrict__ feat)
{
    __shared__ float T[64][65];
    const int tid = threadIdx.x;
    const int o   = tid & 63;
    const int r4  = tid >> 6;
    const int pt  = blockIdx.x;
    const int ocb = blockIdx.y * 64;
    const float b = bias[ocb + o];
    #pragma unroll
    for (int i = 0; i < 16; ++i) {
        const int pl = r4 + i * 4;
        const int px = pt * 64 + pl;
        if (px < NPIX) {
            float s = 0.f;
            #pragma unroll
            for (int k = 0; k < CS; ++k)
                s += part[((size_t)k * NPIX + px) * 512 + ocb + o];
            s += b;
            s = (s >= 0.f) ? s : 0.01f * s;
            T[pl][o] = s;
        }
    }
    __syncthreads();
    const int pl = tid & 63;
    const int px = pt * 64 + pl;
    if (px < NPIX) {
        #pragma unroll
        for (int i = 0; i < 16; ++i) {
            const int ocl = r4 + i * 4;
            feat[(size_t)(ocb + ocl) * NPIX + px] = T[pl][ocl];
        }
    }
}

// ---------------- 1x1 heads: 4-wave cin split + LDS tree reduce ------------
__global__ __launch_bounds__(256) void conv1x1_heads(
    const float* __restrict__ feat,
    const float* __restrict__ rw, const float* __restrict__ rb,
    const float* __restrict__ cw, const float* __restrict__ cb,
    float* __restrict__ regcls)   // (54, 2500)
{
    __shared__ float sAcc[3][18][64];
    const int tid  = threadIdx.x;
    const int lane = tid & 63;
    const int wv   = tid >> 6;
    const int pix0 = blockIdx.x * 64 + lane;
    const bool act = (pix0 < NPIX);
    const int pix  = act ? pix0 : (NPIX - 1);
    const int chunk = blockIdx.y;
    const float* wb; const float* bb; int ocbase;
    if (chunk == 0)      { wb = rw;            bb = rb;      ocbase = 0;  }
    else if (chunk == 1) { wb = rw + 18 * 512; bb = rb + 18; ocbase = 18; }
    else                 { wb = cw;            bb = cb;      ocbase = 36; }

    float acc[18];
    #pragma unroll
    for (int k = 0; k < 18; ++k) acc[k] = 0.f;

    const int c0 = wv * 128;
    for (int cin = c0; cin < c0 + 128; ++cin) {
        const float v = feat[(size_t)cin * NPIX + pix];
        #pragma unroll
        for (int k = 0; k < 18; ++k)
            acc[k] = fmaf(wb[k * 512 + cin], v, acc[k]);
    }
    if (wv > 0) {
        #pragma unroll
        for (int k = 0; k < 18; ++k) sAcc[wv - 1][k][lane] = acc[k];
    }
    __syncthreads();
    if (wv == 0 && act) {
        #pragma unroll
        for (int k = 0; k < 18; ++k) {
            float s = acc[k];
            s += sAcc[0][k][lane];
            s += sAcc[1][k][lane];
            s += sAcc[2][k][lane];
            regcls[(size_t)(ocbase + k) * NPIX + pix] = s + bb[k];
        }
    }
}

// ---------------- decode: anchors, softmax score, sortable key -------------
// Also zero-inits rank[] (replaces a separate memset dispatch).
__global__ __launch_bounds__(256) void decodeK(
    const float* __restrict__ regcls,
    float4* __restrict__ boxes,
    unsigned long long* __restrict__ keys,
    int* __restrict__ rank)
{
    const int i = blockIdx.x * 256 + threadIdx.x;
    if (i >= NANCH) {
        if (i < NKEY) keys[i] = 0xFFFFFFFFFFFFFFFFull;  // sentinel: > all keys
        return;
    }
    rank[i] = 0;
    const int pos = i / 9;
    const int a   = i - pos * 9;
    const int hh  = pos / 50;
    const int wwp = pos - hh * 50;
    const int r = a / 3, s = a - r * 3;

    const float base_s[3] = {128.f, 256.f, 512.f};
    const float sq [3] = {0.70710678118654752440f, 1.0f, 1.41421356237309504880f};
    const float sqi[3] = {1.41421356237309504880f, 1.0f, 0.70710678118654752440f};
    const float hs = base_s[s] * sq[r];
    const float ws = base_s[s] * sqi[r];
    const float cx = (float)(hh * 16 + 8);    // cx indexed by h (reference quirk)
    const float cy = (float)(wwp * 16 + 8);
    const float ax = cx - ws * 0.5f;
    const float ay = cy - hs * 0.5f;

    const float pr0 = regcls[(size_t)(a * 4 + 0) * NPIX + pos];
    const float pr1 = regcls[(size_t)(a * 4 + 1) * NPIX + pos];
    const float pr2 = regcls[(size_t)(a * 4 + 2) * NPIX + pos];
    const float pr3 = regcls[(size_t)(a * 4 + 3) * NPIX + pos];
    const float c0  = regcls[(size_t)(36 + a * 2 + 0) * NPIX + pos];
    const float c1  = regcls[(size_t)(36 + a * 2 + 1) * NPIX + pos];

    const float m  = fmaxf(c0, c1);
    const float e0 = expf(c0 - m);
    const float e1 = expf(c1 - m);
    const float score = e1 / (e0 + e1);

    const float t0 = pr0 + ax;
    const float t1 = pr1 + ay;
    const float hi = 799.0f;
    const float rx1 = fminf(fmaxf(t0, 0.f), hi);
    const float ry1 = fminf(fmaxf(t1, 0.f), hi);
    const float rx2 = fminf(fmaxf((t0 + pr2) + ws, 0.f), hi);
    const float ry2 = fminf(fmaxf((t1 + pr3) + hs, 0.f), hi);
    const float bw = pr2 + ws;
    const float bh = pr3 + hs;
    const bool valid = (bw >= 16.f) && (bh >= 16.f);
    const float sc = valid ? score : -__builtin_inff();

    unsigned u = __float_as_uint(sc);
    u = (u & 0x80000000u) ? ~u : (u | 0x80000000u);  // monotone ascending map
    const unsigned k32 = ~u;                          // descending score
    keys[i]  = ((unsigned long long)k32 << 32) | (unsigned)i;  // tie: asc index
    boxes[i] = make_float4(rx1, ry1, rx2, ry2);
}

// ---------------- O(N^2) rank (stable argsort position) --------------------
__global__ __launch_bounds__(256) void rankK(
    const unsigned long long* __restrict__ keys, int* __restrict__ rank)
{
    const int i = blockIdx.x * 256 + threadIdx.x;
    const unsigned long long my = (i < NANCH) ? keys[i] : 0ull;
    const unsigned long long* kj = keys + blockIdx.y * 2816;
    int cnt = 0;
    for (int t = 0; t < 2816; t += 8) {
        #pragma unroll
        for (int q = 0; q < 8; ++q)
            cnt += (kj[t + q] < my) ? 1 : 0;
    }
    if (i < NANCH) atomicAdd(&rank[i], cnt);
}

__global__ __launch_bounds__(256) void scatterK(
    const float4* __restrict__ boxes, const int* __restrict__ rank,
    float4* __restrict__ sboxes)
{
    const int i = blockIdx.x * 256 + threadIdx.x;
    if (i < NANCH) {
        const int r = rank[i];
        if (r < PRE) sboxes[r] = boxes[i];
    }
}

// ---------------- NMS suppression bitmask (reference bug replicated) -------
__global__ __launch_bounds__(256) void nmsMaskK(
    const float4* __restrict__ sb, unsigned long long* __restrict__ mask)
{
    __shared__ float sx1[JCHUNK], sy1[JCHUNK], sx2[JCHUNK], sy2[JCHUNK], sar[JCHUNK];
    const int tid = threadIdx.x;
    const int jbase = blockIdx.y * JCHUNK;
    for (int t = tid; t < JCHUNK; t += 256) {
        const int j = jbase + t;
        if (j < PRE) {
            const float4 b = sb[j];
            sx1[t] = b.x; sy1[t] = b.y; sx2[t] = b.z; sy2[t] = b.w;
            sar[t] = (b.z - b.x + 1.f) * (b.w - b.y + 1.f);
        } else {
            sx1[t] = 0.f; sy1[t] = 0.f; sx2[t] = -1.f; sy2[t] = 0.f; sar[t] = 0.f;
        }
    }
    __syncthreads();
    const int i = blockIdx.x * 16 + (tid >> 4);
    const float4 bi = sb[i];
    const float x1 = bi.x, y1 = bi.y, x2 = bi.z, y2 = bi.w;
    const float ar = (x2 - x1 + 1.f) * (y2 - y1 + 1.f);
    for (int w = (tid & 15); w < 24; w += 16) {
        unsigned long long bits = 0ull;
        const int l0 = w * 64;
        for (int u = 0; u < 64; ++u) {
            const int j = jbase + l0 + u;
            if (j > i && j < PRE) {
                const int l = l0 + u;
                const float xx1 = fmaxf(x1, sx1[l]);
                const float yy1 = fmaxf(y1, sy1[l]);
                const float xx2 = fminf(x2, sx2[l]);
                const float yy2 = fmaxf(y2, sy2[l]);        // reference bug: max
                const float wv = fmaxf(0.f, xx2 - xx1 + 1.f);
                const float hv = fmaxf(0.f, yy2 - yy1 + 1.f);
                const float inter = wv * hv;
                const float ov = inter / ((ar + sar[l]) - inter);  // precise div
                if (ov > 0.7f) bits |= (1ull << u);
            }
        }
        mask[(size_t)i * MW + blockIdx.y * 24 + w] = bits;
    }
}

// ---------------- word-serial NMS scan + output (single wave) --------------
__global__ __launch_bounds__(64) void nmsScanOutK(
    const unsigned long long* __restrict__ mask,
    const float4* __restrict__ sb,
    float* __restrict__ out)
{
    __shared__ int sKept[300];
    __shared__ unsigned long long sKeepW[MASKW];
    const int lane = threadIdx.x;

    unsigned long long rem0 = 0ull, rem1 = 0ull;   // lane l: words l, 64+l
    int cnt = 0;
    int done = 0;

    unsigned long long diag = mask[(size_t)lane * MW + 0];   // block 0 diag

    for (int g = 0; g < MASKW && !done; ++g) {
        unsigned long long diag_next = 0ull;
        if (g + 1 < MASKW) {
            const int r2 = (g + 1) * 64 + lane;
            if (r2 < PRE) diag_next = mask[(size_t)r2 * MW + (g + 1)];
        }
        unsigned long long cur;
        {
            unsigned lo, hi;
            if (g < 64) {
                lo = __builtin_amdgcn_readlane((unsigned)rem0, g);
                hi = __builtin_amdgcn_readlane((unsigned)(rem0 >> 32), g);
            } else {
                lo = __builtin_amdgcn_readlane((unsigned)rem1, g - 64);
                hi = __builtin_amdgcn_readlane((unsigned)(rem1 >> 32), g - 64);
            }
            cur = ((unsigned long long)hi << 32) | lo;
        }
        const unsigned long long valid =
            (g == MASKW - 1) ? 0x0000FFFFFFFFFFFFull : ~0ull;   // 48 tail bits

        // ---- in-block serial loop: pure ALU, zero memory ops ----
        unsigned long long kb = 0ull;
        for (;;) {
            const unsigned long long nd = (~cur) & valid;
            if (!nd) break;
            const int b = __builtin_ctzll(nd);     // unsuppressed => KEPT
            if (lane == 0 && cnt < 300) sKept[cnt] = g * 64 + b;
            ++cnt;
            kb |= (1ull << b);
            if (cnt >= 300) { done = 1; break; }
            const unsigned dlo = __builtin_amdgcn_readlane((unsigned)diag, b);
            const unsigned dhi = __builtin_amdgcn_readlane((unsigned)(diag >> 32), b);
            cur |= (1ull << b) | (((unsigned long long)dhi << 32) | dlo);
        }
        if (lane == 0) sKeepW[g] = kb;

        // ---- batched kept-row loads: OR their full rows into rem ----
        if (!done && kb) {
            int kbit[KSLOT];
            unsigned long long t = kb;
            #pragma unroll
            for (int s = 0; s < KSLOT; ++s) {
                kbit[s] = t ? __builtin_ctzll(t) : 64;
                t &= t - 1;
            }
            unsigned long long a0 = 0ull, a1 = 0ull;
            #pragma unroll
            for (int s = 0; s < KSLOT; ++s) {
                if (kbit[s] < 64) {                // wave-uniform branch
                    const unsigned long long* pr =
                        mask + (size_t)(g * 64 + kbit[s]) * MW;
                    a0 |= pr[lane];
                    a1 |= (lane < MASKW - 64) ? pr[64 + lane] : 0ull;
                }
            }
            while (t) {                             // >KSLOT overflow (rare)
                const int b = __builtin_ctzll(t); t &= t - 1;
                const unsigned long long* pr = mask + (size_t)(g * 64 + b) * MW;
                a0 |= pr[lane];
                a1 |= (lane < MASKW - 64) ? pr[64 + lane] : 0ull;
            }
            rem0 |= a0;
            rem1 |= a1;
        }
        diag = diag_next;
    }

    __syncthreads();

    if (cnt < 300) {                                 // filler: unkept, asc index
        int c = cnt;
        for (int g = 0; g < MASKW && c < 300; ++g) {
            const unsigned long long valid =
                (g == MASKW - 1) ? 0x0000FFFFFFFFFFFFull : ~0ull;
            unsigned long long u = (~sKeepW[g]) & valid;
            while (u && c < 300) {
                const int b = __builtin_ctzll(u); u &= u - 1;
                if (lane == 0) sKept[c] = g * 64 + b;
                ++c;
            }
        }
    }
    __syncthreads();

    for (int s = lane; s < 300; s += 64) {
        const float4 b = sb[sKept[s]];
        out[s * 4 + 0] = b.x;
        out[s * 4 + 1] = b.y;
        out[s * 4 + 2] = b.z - b.x + 1.0f;
        out[s * 4 + 3] = b.w - b.y + 1.0f;
    }
}

// ---------------------------------------------------------------------------
extern "C" void kernel_launch(void* const* d_in, const int* in_sizes, int n_in,
                              void* d_out, int out_size, void* d_ws, size_t ws_size,
                              hipStream_t stream)
{
    (void)in_sizes; (void)n_in; (void)out_size; (void)ws_size;
    const float* x   = (const float*)d_in[0] + (size_t)7 * 512 * NPIX; // batch 7
    const float* cw3 = (const float*)d_in[1];
    const float* cb3 = (const float*)d_in[2];
    const float* rw  = (const float*)d_in[3];
    const float* rb  = (const float*)d_in[4];
    const float* clw = (const float*)d_in[5];
    const float* clb = (const float*)d_in[6];
    float* out = (float*)d_out;

    char* p = (char*)d_ws;
    auto alloc = [&](size_t n) { char* r = p; p += (n + 255) & ~(size_t)255; return r; };
    float*  part   = (float*)alloc((size_t)CS * NPIX * 512 * 4);  // 82 MB
    float*  wtT    = (float*)alloc((size_t)4608 * 512 * 4);       // 9.4 MB
    float*  feat   = (float*)alloc((size_t)512 * NPIX * 4);       // 5.12 MB
    float*  regcls = (float*)alloc((size_t)54 * NPIX * 4);        // 0.54 MB
    // Tail buffers alias the part region: part is dead after reduce_leaky,
    // and all of these are first written at decodeK time or later.
    char* q = (char*)part;
    auto alias = [&](size_t n) { char* r = q; q += (n + 255) & ~(size_t)255; return r; };
    float4* boxes  = (float4*)alias((size_t)NANCH * 16);          // 0.36 MB
    unsigned long long* keys = (unsigned long long*)alias((size_t)NKEY * 8);
    int*    rank   = (int*)alias((size_t)NANCH * 4);
    float4* sboxes = (float4*)alias((size_t)PRE * 16);
    unsigned long long* mask = (unsigned long long*)alias((size_t)PRE * MW * 8); // 4.6 MB

    transposeW    <<<dim3(72, 8), 256, 0, stream>>>(cw3, wtT);
    conv3x3_v3    <<<dim3(4, 50, CS), 64, 0, stream>>>(x, wtT, part);
    reduce_leaky  <<<dim3(40, 8), 256, 0, stream>>>(part, cb3, feat);
    conv1x1_heads <<<dim3(40, 3), 256, 0, stream>>>(feat, rw, rb, clw, clb, regcls);
    decodeK       <<<88, 256, 0, stream>>>(regcls, boxes, keys, rank);
    rankK         <<<dim3(88, 8), 256, 0, stream>>>(keys, rank);
    scatterK      <<<88, 256, 0, stream>>>(boxes, rank, sboxes);
    nmsMaskK      <<<dim3(375, 4), 256, 0, stream>>>(sboxes, mask);
    nmsScanOutK   <<<1, 64, 0, stream>>>(mask, sboxes, out);
}